// Round 4
// baseline (21816.103 us; speedup 1.0000x reference)
//
#include <hip/hip_runtime.h>

// RNN-VAE on MI355X. 16 WGs x 16 batch rows, 8 waves/WG (2/SIMD, 256 VGPR).
// R4: gate-aligned wave mapping (wave owns all 4 gates of its 32 h-cols ->
// in-register c/h update, 1 barrier/step); U kt0,1 pinned in LDS (128KB);
// enc pins U kt2,3 in regs, dec pins U kt2; remaining slices streamed via a
// 32-VGPR buffer interleaved with MFMAs. Fix vs R3: woutlds full 768-vec
// load (was 384 -> garbage W_out in fused out-proj); enc x-prefetch removed;
// register pins trimmed to fit 256 VGPR without spill/remat.

typedef __bf16 bf16x8 __attribute__((ext_vector_type(8)));
typedef float f32x4 __attribute__((ext_vector_type(4)));
typedef unsigned int uint4v __attribute__((ext_vector_type(4)));

#define DI __device__ __forceinline__

DI unsigned short f2bf(float f) {            // fp32 -> bf16 RNE
  unsigned int u = __float_as_uint(f);
  u += 0x7fffu + ((u >> 16) & 1u);
  return (unsigned short)(u >> 16);
}
DI float sigf(float v) { return 1.0f / (1.0f + __expf(-v)); }

union FragU { bf16x8 v; unsigned short us[8]; };

DI f32x4 mfma16(bf16x8 a, bf16x8 b, f32x4 c) {
  // D[row=(lane>>4)*4+q][col=lane&15]; A[row=lane&15][k=(lane>>4)*8+j]
  return __builtin_amdgcn_mfma_f32_16x16x32_bf16(a, b, c, 0, 0, 0);
}

// ---- weight fragment packing: src (K x N fp32, row-major) ->
// frag[j] = src[kt*32+(lane>>4)*8+j][nt*16+(lane&15)], flat idx (kt*NT+nt)*64+lane
__global__ void pack_frags(const float* __restrict__ src,
                           unsigned short* __restrict__ dst, int K, int N) {
  int KT = K >> 5, NT = N >> 4;
  int total = KT * NT * 64;
  for (int idx = blockIdx.x * blockDim.x + threadIdx.x; idx < total;
       idx += gridDim.x * blockDim.x) {
    int lane = idx & 63;
    int fi = idx >> 6;
    int nt = fi % NT;
    int kt = fi / NT;
    int r0 = kt * 32 + (lane >> 4) * 8;
    int col = nt * 16 + (lane & 15);
    unsigned int w[4];
#pragma unroll
    for (int p = 0; p < 4; ++p) {
      unsigned int lo = f2bf(src[(size_t)(r0 + 2 * p) * N + col]);
      unsigned int hi = f2bf(src[(size_t)(r0 + 2 * p + 1) * N + col]);
      w[p] = lo | (hi << 16);
    }
    *(uint4v*)(dst + (size_t)idx * 8) = (uint4v){w[0], w[1], w[2], w[3]};
  }
}

// ---- per-(b,t) nonzero mask: flags[b>>4][t] bit (b&15) ----
__global__ void mask_flags(const float* __restrict__ x,
                           unsigned int* __restrict__ flags) {
  const int t = blockIdx.x;          // 1024
  const int b = threadIdx.x;         // 256
  const float* p = x + ((size_t)b * 1024 + t) * 128;
  bool nz = false;
#pragma unroll 8
  for (int k = 0; k < 32; ++k) {
    float4 v = *(const float4*)(p + k * 4);
    nz = nz || v.x != 0.f || v.y != 0.f || v.z != 0.f || v.w != 0.f;
  }
  unsigned long long bal = __ballot((int)nz);
  if ((threadIdx.x & 15) == 0)
    flags[(size_t)(b >> 4) * 1024 + t] =
        (unsigned int)((bal >> (threadIdx.x & 48)) & 0xFFFFull);
}

#define ISSUE(P, KT) do { _Pragma("unroll")                                 \
    for (int f = 0; f < 8; ++f) buf[f] = (P)[((KT) * 64 + ntf[f]) * 64];    \
  } while (0)
#define USE_X(KT) do { _Pragma("unroll")                                    \
    for (int f = 0; f < 8; ++f) acc[f] = mfma16(xf[KT].v, buf[f], acc[f]);  \
  } while (0)
#define USE_H(KT) do { _Pragma("unroll")                                    \
    for (int f = 0; f < 8; ++f) acc[f] = mfma16(hfr[KT], buf[f], acc[f]);   \
  } while (0)
#define ULDS_H(KT) do { _Pragma("unroll")                                   \
    for (int f = 0; f < 8; ++f) {                                           \
      bf16x8 u_ = *(const bf16x8*)&ulds[(((KT) * 64 + ntf[f]) * 64 + lane) * 8]; \
      acc[f] = mfma16(hfr[KT], u_, acc[f]); }                               \
  } while (0)
#define UPIN_H(K) do { _Pragma("unroll")                                    \
    for (int f = 0; f < 8; ++f)                                             \
      acc[f] = mfma16(hfr[(K) + 2], upin[K][f], acc[f]);                    \
  } while (0)

// =========================== encoder ======================================
__global__ __launch_bounds__(512, 2)
void enc_rnn(const float* __restrict__ x,              // [256][1024][128]
             const unsigned short* __restrict__ Wef,   // 128x1024 frags
             const unsigned short* __restrict__ Uef,   // 256x1024 frags
             const float* __restrict__ benc,
             const unsigned int* __restrict__ flags,   // [16][1024]
             unsigned short* __restrict__ hfin) {
  __shared__ __align__(16) unsigned short ulds[2 * 64 * 64 * 8];  // U kt0,1 128KB
  __shared__ __align__(16) unsigned short hfrag[2 * 8 * 64 * 8];  // h dbuf 16KB

  const int tid = threadIdx.x;
  const int w = tid >> 6, lane = tid & 63;
  const int l15 = lane & 15, lkg = lane >> 4;
  const int wg = blockIdx.x, b0 = wg * 16;
  int ntf[8];
#pragma unroll
  for (int f = 0; f < 8; ++f) ntf[f] = (f >> 1) * 16 + 2 * w + (f & 1);

#pragma unroll
  for (int k = 0; k < 16; ++k)
    ((uint4v*)ulds)[tid + k * 512] = ((const uint4v*)Uef)[tid + k * 512];
  ((uint4v*)hfrag)[tid] = (uint4v){0u, 0u, 0u, 0u};
  ((uint4v*)hfrag)[tid + 512] = (uint4v){0u, 0u, 0u, 0u};

  const bf16x8* Wl = (const bf16x8*)Wef + lane;
  const bf16x8* Ul = (const bf16x8*)Uef + lane;
  const unsigned int* flagp = flags + (size_t)wg * 1024;

  bf16x8 upin[2][8];                       // U kt2,3 reg-pinned
#pragma unroll
  for (int k = 0; k < 2; ++k)
#pragma unroll
    for (int f = 0; f < 8; ++f) upin[k][f] = Ul[((k + 2) * 64 + ntf[f]) * 64];

  float bfr[8];
#pragma unroll
  for (int f = 0; f < 8; ++f) bfr[f] = benc[ntf[f] * 16 + l15];

  float c8[8];
  unsigned short hreg[8];
#pragma unroll
  for (int i = 0; i < 8; ++i) { c8[i] = 0.f; hreg[i] = 0; }

  const float* xbase = x + (size_t)(b0 + l15) * 1024 * 128 + lkg * 8;

  bf16x8 buf[8], hfr[8];
  int hb = 0;

  __syncthreads();

  for (int t = 0; t < 1024; ++t) {
    const unsigned int flag = flagp[t];
    if (flag == 0u) continue;          // uniform: carry h,c

    const float* xp = xbase + (size_t)t * 128;
    FragU xf[4];
#pragma unroll
    for (int kt = 0; kt < 4; ++kt) {
      float4 a = *(const float4*)(xp + kt * 32);
      float4 b = *(const float4*)(xp + kt * 32 + 4);
      xf[kt].us[0] = f2bf(a.x); xf[kt].us[1] = f2bf(a.y);
      xf[kt].us[2] = f2bf(a.z); xf[kt].us[3] = f2bf(a.w);
      xf[kt].us[4] = f2bf(b.x); xf[kt].us[5] = f2bf(b.y);
      xf[kt].us[6] = f2bf(b.z); xf[kt].us[7] = f2bf(b.w);
    }

    ISSUE(Wl, 0);

    const unsigned short* hrd = hfrag + hb * 4096;
#pragma unroll
    for (int k = 0; k < 8; ++k) hfr[k] = *(const bf16x8*)&hrd[(k * 64 + lane) * 8];

    f32x4 acc[8];
#pragma unroll
    for (int f = 0; f < 8; ++f) acc[f] = (f32x4){bfr[f], bfr[f], bfr[f], bfr[f]};

    ULDS_H(0);
    ULDS_H(1);

    USE_X(0); ISSUE(Wl, 1);
    UPIN_H(0);
    USE_X(1); ISSUE(Wl, 2);
    UPIN_H(1);
    USE_X(2); ISSUE(Wl, 3);
    USE_X(3); ISSUE(Ul, 4);
    USE_H(4); ISSUE(Ul, 5);
    USE_H(5); ISSUE(Ul, 6);
    USE_H(6); ISSUE(Ul, 7);
    USE_H(7);

    // in-register gate fusion + h broadcast (masked rows carry h,c)
    unsigned short* hwr = hfrag + (hb ^ 1) * 4096;
#pragma unroll
    for (int p = 0; p < 2; ++p) {
#pragma unroll
      for (int q = 0; q < 4; ++q) {
        float iv = sigf(acc[0 * 2 + p][q]);
        float fv = sigf(acc[1 * 2 + p][q]);
        float gv = fmaxf(acc[2 * 2 + p][q], 0.f);
        float ov = sigf(acc[3 * 2 + p][q]);
        float cn = fv * c8[p * 4 + q] + iv * gv;
        float hn = ov * fmaxf(cn, 0.f);
        bool m = (flag >> (lkg * 4 + q)) & 1u;
        c8[p * 4 + q] = m ? cn : c8[p * 4 + q];
        unsigned short hh = m ? f2bf(hn) : hreg[p * 4 + q];
        hreg[p * 4 + q] = hh;
        hwr[((w * 64 + (p * 2 + (l15 >> 3)) * 16 + lkg * 4 + q)) * 8 + (l15 & 7)] = hh;
      }
    }
    __syncthreads();
    hb ^= 1;
  }

  ((uint4v*)hfin)[(size_t)wg * 512 + tid] =
      ((const uint4v*)(hfrag + hb * 4096))[tid];
}

// =========================== decoder ======================================
__global__ __launch_bounds__(512, 2)
void dec_rnn(const float* __restrict__ x,
             const unsigned short* __restrict__ Wd0f,   // 64x1024 frags
             const unsigned short* __restrict__ WdLf,   // 256x1024 frags
             const unsigned short* __restrict__ Udf,    // 256x1024 frags
             const float* __restrict__ bdec,
             const unsigned short* __restrict__ Wof,    // 256x64 frags
             const float* __restrict__ bout,
             const unsigned short* __restrict__ hfin,
             float* __restrict__ out) {
  __shared__ __align__(16) unsigned short ulds[2 * 64 * 64 * 8];  // U kt0,1 128KB
  __shared__ __align__(16) unsigned short hfrag[2 * 8 * 64 * 8];  // 16KB
  __shared__ __align__(16) unsigned short woutlds[12 * 64 * 8];   // Wout kt0..2 12KB

  const int tid = threadIdx.x;
  const int w = tid >> 6, lane = tid & 63;
  const int l15 = lane & 15, lkg = lane >> 4;
  const int wg = blockIdx.x, b0 = wg * 16;
  int ntf[8];
#pragma unroll
  for (int f = 0; f < 8; ++f) ntf[f] = (f >> 1) * 16 + 2 * w + (f & 1);

#pragma unroll
  for (int k = 0; k < 16; ++k)
    ((uint4v*)ulds)[tid + k * 512] = ((const uint4v*)Udf)[tid + k * 512];
  ((uint4v*)hfrag)[tid] = (uint4v){0u, 0u, 0u, 0u};
  ((uint4v*)hfrag)[tid + 512] = (uint4v){0u, 0u, 0u, 0u};
  // Wout kt0..2 -> LDS: 12KB = 768 uint4v (R3 bug: only 384 were loaded)
  ((uint4v*)woutlds)[tid] = ((const uint4v*)Wof)[tid];
  if (tid < 256)
    ((uint4v*)woutlds)[512 + tid] = ((const uint4v*)Wof)[512 + tid];

  const bf16x8* W0l = (const bf16x8*)Wd0f + lane;
  const bf16x8* WLl = (const bf16x8*)WdLf + lane;
  const bf16x8* Ul  = (const bf16x8*)Udf + lane;

  bf16x8 upin[1][8];                        // U kt2 reg-pinned
#pragma unroll
  for (int f = 0; f < 8; ++f) upin[0][f] = Ul[(2 * 64 + ntf[f]) * 64];

  // lat = b_dec + h_fin @ W_dec[64:], packed to bf16 pairs
  uint2 latw[8];
  {
    f32x4 lat[8];
#pragma unroll
    for (int f = 0; f < 8; ++f) {
      float bd = bdec[ntf[f] * 16 + l15];
      lat[f] = (f32x4){bd, bd, bd, bd};
    }
#pragma unroll
    for (int kt = 0; kt < 8; ++kt) {
      bf16x8 hv = *(const bf16x8*)(hfin + (size_t)wg * 4096 +
                                   (size_t)(kt * 64 + lane) * 8);
#pragma unroll
      for (int f = 0; f < 8; ++f)
        lat[f] = mfma16(hv, WLl[(kt * 64 + ntf[f]) * 64], lat[f]);
    }
#pragma unroll
    for (int f = 0; f < 8; ++f) {
      latw[f].x = (unsigned int)f2bf(lat[f][0]) | ((unsigned int)f2bf(lat[f][1]) << 16);
      latw[f].y = (unsigned int)f2bf(lat[f][2]) | ((unsigned int)f2bf(lat[f][3]) << 16);
    }
  }

  bf16x8 wop[5];                            // Wout kt3..7 for out-waves
  if (w < 4) {
#pragma unroll
    for (int k = 0; k < 5; ++k)
      wop[k] = ((const bf16x8*)Wof)[((k + 3) * 4 + w) * 64 + lane];
  }
  const float bo = bout[(w & 3) * 16 + l15];

  float c8[8];
#pragma unroll
  for (int i = 0; i < 8; ++i) c8[i] = 0.f;

  const float* xbase = x + (size_t)(b0 + l15) * 1024 * 128 + lkg * 8;

  bf16x8 buf[8], hfr[8];
  float4 xa[2][2];
  xa[0][0] = *(const float4*)(xbase);      xa[0][1] = *(const float4*)(xbase + 4);
  xa[1][0] = *(const float4*)(xbase + 32); xa[1][1] = *(const float4*)(xbase + 36);
  int hb = 0;

  __syncthreads();

  for (int t = 0; t < 1024; ++t) {
    ISSUE(W0l, 0);

    const unsigned short* hrd = hfrag + hb * 4096;
#pragma unroll
    for (int k = 0; k < 8; ++k) hfr[k] = *(const bf16x8*)&hrd[(k * 64 + lane) * 8];

    f32x4 acc[8];
#pragma unroll
    for (int f = 0; f < 8; ++f)
      acc[f] = (f32x4){__uint_as_float(latw[f].x << 16),
                       __uint_as_float(latw[f].x & 0xFFFF0000u),
                       __uint_as_float(latw[f].y << 16),
                       __uint_as_float(latw[f].y & 0xFFFF0000u)};

    ULDS_H(0);
    ULDS_H(1);

    FragU xf[2];
#pragma unroll
    for (int kt = 0; kt < 2; ++kt) {
      xf[kt].us[0] = f2bf(xa[kt][0].x); xf[kt].us[1] = f2bf(xa[kt][0].y);
      xf[kt].us[2] = f2bf(xa[kt][0].z); xf[kt].us[3] = f2bf(xa[kt][0].w);
      xf[kt].us[4] = f2bf(xa[kt][1].x); xf[kt].us[5] = f2bf(xa[kt][1].y);
      xf[kt].us[6] = f2bf(xa[kt][1].z); xf[kt].us[7] = f2bf(xa[kt][1].w);
    }

    USE_X(0); ISSUE(W0l, 1);
    UPIN_H(0);
    USE_X(1); ISSUE(Ul, 3);
    USE_H(3); ISSUE(Ul, 4);
    USE_H(4); ISSUE(Ul, 5);
    USE_H(5); ISSUE(Ul, 6);
    USE_H(6); ISSUE(Ul, 7);
    USE_H(7);

    if (t < 1023) {             // prefetch x for t+1
      const float* xq = xbase + (size_t)(t + 1) * 128;
      xa[0][0] = *(const float4*)(xq);      xa[0][1] = *(const float4*)(xq + 4);
      xa[1][0] = *(const float4*)(xq + 32); xa[1][1] = *(const float4*)(xq + 36);
    }

    unsigned short* hwr = hfrag + (hb ^ 1) * 4096;
#pragma unroll
    for (int p = 0; p < 2; ++p) {
#pragma unroll
      for (int q = 0; q < 4; ++q) {
        float iv = sigf(acc[0 * 2 + p][q]);
        float fv = sigf(acc[1 * 2 + p][q]);
        float gv = fmaxf(acc[2 * 2 + p][q], 0.f);
        float ov = sigf(acc[3 * 2 + p][q]);
        float cn = fv * c8[p * 4 + q] + iv * gv;
        float hn = ov * fmaxf(cn, 0.f);
        c8[p * 4 + q] = cn;
        hwr[((w * 64 + (p * 2 + (l15 >> 3)) * 16 + lkg * 4 + q)) * 8 + (l15 & 7)] =
            f2bf(hn);
      }
    }
    __syncthreads();
    hb ^= 1;

    if (w < 4) {                // fused out-proj on h[t] (= hfrag[hb])
      const unsigned short* hrd2 = hfrag + hb * 4096;
      f32x4 oa = {bo, bo, bo, bo};
#pragma unroll
      for (int kt = 0; kt < 8; ++kt) {
        bf16x8 h2 = *(const bf16x8*)&hrd2[(kt * 64 + lane) * 8];
        bf16x8 wf;
        if (kt < 3) wf = *(const bf16x8*)&woutlds[((kt * 4 + w) * 64 + lane) * 8];
        else        wf = wop[kt - 3];
        oa = mfma16(h2, wf, oa);
      }
#pragma unroll
      for (int q = 0; q < 4; ++q)
        out[((size_t)(b0 + lkg * 4 + q) * 1024 + t) * 64 + w * 16 + l15] = oa[q];
    }
  }
}

extern "C" void kernel_launch(void* const* d_in, const int* in_sizes, int n_in,
                              void* d_out, int out_size, void* d_ws, size_t ws_size,
                              hipStream_t stream) {
  const float* inputs = (const float*)d_in[0];
  const float* W_enc  = (const float*)d_in[1];
  const float* U_enc  = (const float*)d_in[2];
  const float* b_enc  = (const float*)d_in[3];
  const float* W_dec  = (const float*)d_in[4];
  const float* U_dec  = (const float*)d_in[5];
  const float* b_dec  = (const float*)d_in[6];
  const float* W_out  = (const float*)d_in[7];
  const float* b_out  = (const float*)d_in[8];

  char* ws = (char*)d_ws;
  unsigned short* Uef  = (unsigned short*)(ws + 0);        // 512KB
  unsigned short* Udf  = (unsigned short*)(ws + 524288);   // 512KB
  unsigned short* Wef  = (unsigned short*)(ws + 1048576);  // 256KB
  unsigned short* Wd0f = (unsigned short*)(ws + 1310720);  // 128KB
  unsigned short* WdLf = (unsigned short*)(ws + 1441792);  // 512KB
  unsigned short* Wof  = (unsigned short*)(ws + 1966080);  // 32KB
  unsigned short* hfin = (unsigned short*)(ws + 1998848);  // 128KB
  unsigned int*   flags = (unsigned int*)(ws + 2129920);   // 64KB

  mask_flags<<<1024, 256, 0, stream>>>(inputs, flags);
  pack_frags<<<128, 256, 0, stream>>>(U_enc, Uef, 256, 1024);
  pack_frags<<<128, 256, 0, stream>>>(U_dec, Udf, 256, 1024);
  pack_frags<<<128, 256, 0, stream>>>(W_enc, Wef, 128, 1024);
  pack_frags<<<128, 256, 0, stream>>>(W_dec, Wd0f, 64, 1024);
  pack_frags<<<128, 256, 0, stream>>>(W_dec + 64 * 1024, WdLf, 256, 1024);
  pack_frags<<<32, 256, 0, stream>>>(W_out, Wof, 256, 64);

  enc_rnn<<<16, 512, 0, stream>>>(inputs, Wef, Uef, b_enc, flags, hfin);
  dec_rnn<<<16, 512, 0, stream>>>(inputs, Wd0f, WdLf, Udf, b_dec, Wof, b_out,
                                  hfin, (float*)d_out);
}